// Round 8
// baseline (174.110 us; speedup 1.0000x reference)
//
#include <hip/hip_runtime.h>
#include <math.h>

#define NTOK 384
#define DIM  128
#define HEADS 4
#define DHEAD 64
#define INNER 256
#define DEPTH 3
#define EDGE 8
#define FFD 512

__device__ __forceinline__ float wave_sum64(float v){
#pragma unroll
  for (int m = 32; m >= 1; m >>= 1) v += __shfl_xor(v, m, 64);
  return v;
}
__device__ __forceinline__ float wave_max64(float v){
#pragma unroll
  for (int m = 32; m >= 1; m >>= 1) v = fmaxf(v, __shfl_xor(v, m, 64));
  return v;
}

// XCD-pinned row mapping: 384 = 8 XCDs x 48 rows.
__device__ __forceinline__ int swz_row(int id){ return (id & 7) * 48 + (id >> 3); }

// Rotary for one (i, d): numpy float32 semantics via double precision then round.
__device__ __forceinline__ void rotary_val(int i, int d, float* c, float* s){
  int j = d >> 1;
  double ex = (double)(2 * j) / 64.0;
  float p = (float)pow(10000.0, ex);
  float inv = 1.0f / p;
  float f = (float)i * inv;
  double fd = (double)f;
  *c = (float)cos(fd);
  *s = (float)sin(fd);
}

// QKV (+rotary, qWe, qbe) for ONE row. t<384 active. Full K=128 per thread.
// K written transposed to kbT[h][d][j]. (Used by layer-0 k_lnqkv only.)
__device__ __forceinline__ void qkv_row_512(
    int i, int t, const float* __restrict__ snx,
    const float* __restrict__ Wq, const float* __restrict__ bq,
    const float* __restrict__ Wkv, const float* __restrict__ bkv,
    const float* __restrict__ We, const float* __restrict__ be,
    const float* __restrict__ cosRow, const float* __restrict__ sinRow,
    float* __restrict__ qb_, float* __restrict__ kbT, float* __restrict__ vb_,
    float* __restrict__ qWeB, float* __restrict__ qbeB)
{
  if (t >= 384) return;
  const float2* Wp; const float* bb; int pcol; int stride;
  if (t < 128)      { Wp = (const float2*)Wq + t;              stride = 128; bb = bq;        pcol = t; }
  else if (t < 256) { Wp = (const float2*)Wkv + (t - 128);     stride = 256; bb = bkv;       pcol = t - 128; }
  else              { Wp = (const float2*)Wkv + 128 + (t - 256); stride = 256; bb = bkv + 256; pcol = t - 256; }

  float a0 = 0.f, a1 = 0.f;
#pragma unroll 8
  for (int k = 0; k < 128; ++k){
    float2 w = Wp[(size_t)k * stride];
    float xr = snx[k];
    a0 = fmaf(xr, w.x, a0); a1 = fmaf(xr, w.y, a1);
  }
  a0 += bb[2 * pcol]; a1 += bb[2 * pcol + 1];

  if (t < 256){
    int dloc = (2 * pcol) & 63;
    float c = cosRow[dloc], s = sinRow[dloc];
    float r0 = a0 * c - a1 * s;
    float r1 = a1 * c + a0 * s;
    if (t < 128){
      qb_[i * 256 + 2 * pcol]     = r0;
      qb_[i * 256 + 2 * pcol + 1] = r1;
      int h = pcol >> 5;
#pragma unroll
      for (int cc = 0; cc < 8; ++cc){
        float pr = r0 * We[cc * 256 + 2 * pcol] + r1 * We[cc * 256 + 2 * pcol + 1];
#pragma unroll
        for (int m = 16; m >= 1; m >>= 1) pr += __shfl_xor(pr, m, 32);
        if ((t & 31) == 0) qWeB[(h * NTOK + i) * 8 + cc] = pr;
      }
      float pb = r0 * be[2 * pcol] + r1 * be[2 * pcol + 1];
#pragma unroll
      for (int m = 16; m >= 1; m >>= 1) pb += __shfl_xor(pb, m, 32);
      if ((t & 31) == 0) qbeB[h * NTOK + i] = pb;
    } else {
      int h = pcol >> 5, d0 = 2 * (pcol & 31);
      kbT[(size_t)(h * 64 + d0) * NTOK + i]     = r0;
      kbT[(size_t)(h * 64 + d0 + 1) * NTOK + i] = r1;
    }
  } else {
    vb_[i * 256 + 2 * pcol]     = a0;
    vb_[i * 256 + 2 * pcol + 1] = a1;
  }
}

// Layer-0: rotary (own row, into LDS + global table) + LN1 + QKV. 512 thr/row.
__global__ __launch_bounds__(512) void k_lnqkv(
    const float* __restrict__ x,
    const float* __restrict__ ls, const float* __restrict__ lb,
    const float* __restrict__ Wq, const float* __restrict__ bq,
    const float* __restrict__ Wkv, const float* __restrict__ bkv,
    const float* __restrict__ We, const float* __restrict__ be,
    float* __restrict__ cosS, float* __restrict__ sinS,
    float* __restrict__ qb_, float* __restrict__ kbT, float* __restrict__ vb_,
    float* __restrict__ qWeB, float* __restrict__ qbeB)
{
  __shared__ float snx[128];
  __shared__ float crow[64], srow[64];
  __shared__ float red[4];
  int i = swz_row(blockIdx.x);
  int t = threadIdx.x;

  if (t >= 448){
    int d = t - 448;
    float c, s;
    rotary_val(i, d, &c, &s);
    crow[d] = c; srow[d] = s;
    cosS[i * 64 + d] = c; sinS[i * 64 + d] = s;
  }
  float xv = (t < 128) ? x[(size_t)i * 128 + t] : 0.f;
  float s = (t < 128) ? wave_sum64(xv) : 0.f;
  if (t == 0)  red[0] = s;
  if (t == 64) red[1] = s;
  __syncthreads();
  float mu = (red[0] + red[1]) * (1.0f / 128.0f);
  float d = xv - mu;
  float s2 = (t < 128) ? wave_sum64(d * d) : 0.f;
  if (t == 0)  red[2] = s2;
  if (t == 64) red[3] = s2;
  __syncthreads();
  if (t < 128){
    float var = (red[2] + red[3]) * (1.0f / 128.0f);
    float rstd = 1.0f / sqrtf(var + 1e-3f);
    snx[t] = d * rstd * ls[t] + lb[t];
  }
  __syncthreads();
  qkv_row_512(i, t, snx, Wq, bq, Wkv, bkv, We, be, crow, srow,
              qb_, kbT, vb_, qWeB, qbeB);
}

// Attention for one (i, h). 384 threads, thread t <-> j=t. K is transposed.
__global__ __launch_bounds__(384) void k_attn(
    const float* __restrict__ qb_, const float* __restrict__ kbT, const float* __restrict__ vb_,
    const float* __restrict__ qWeB, const float* __restrict__ qbeB,
    const float* __restrict__ edges,
    const float* __restrict__ We, const float* __restrict__ be,
    float* __restrict__ aout)
{
  __shared__ float qs[64];
  __shared__ float qw[8];
  __shared__ float qbs_s;
  __shared__ float attnL[NTOK];
  __shared__ float redA[6], redB[6];
  __shared__ float red8[6][8];
  __shared__ float aws[8];
  __shared__ float part[NTOK];

  int id = blockIdx.x;           // 1536 = 8 xcd * (48 rows * 4 heads)
  int xcd = id & 7, loc = id >> 3;
  int i = xcd * 48 + (loc % 48);
  int h = loc / 48;
  int t = threadIdx.x, lane = t & 63, wv = t >> 6;

  if (t < 64) qs[t] = qb_[i * 256 + h * 64 + t];
  else if (t < 72) qw[t - 64] = qWeB[(h * NTOK + i) * 8 + (t - 64)];
  else if (t == 72) qbs_s = qbeB[h * NTOK + i];
  __syncthreads();

  const float* kTp = kbT + (size_t)(h * 64) * NTOK + t;
  float ac0 = 0.f, ac1 = 0.f, ac2 = 0.f, ac3 = 0.f;
#pragma unroll 8
  for (int d = 0; d < 64; d += 4){
    ac0 = fmaf(qs[d],     kTp[(size_t)d * NTOK],       ac0);
    ac1 = fmaf(qs[d + 1], kTp[(size_t)(d + 1) * NTOK], ac1);
    ac2 = fmaf(qs[d + 2], kTp[(size_t)(d + 2) * NTOK], ac2);
    ac3 = fmaf(qs[d + 3], kTp[(size_t)(d + 3) * NTOK], ac3);
  }
  const float* ep = edges + ((size_t)i * NTOK + t) * 8;
  float4 e0 = *(const float4*)ep;
  float4 e1 = *(const float4*)(ep + 4);
  float ed = e0.x * qw[0] + e0.y * qw[1] + e0.z * qw[2] + e0.w * qw[3]
           + e1.x * qw[4] + e1.y * qw[5] + e1.z * qw[6] + e1.w * qw[7];
  float sim = 0.125f * (ac0 + ac1 + ac2 + ac3 + ed + qbs_s);

  float mx = wave_max64(sim);
  if (lane == 0) redA[wv] = mx;
  __syncthreads();
  float gm = fmaxf(fmaxf(fmaxf(redA[0], redA[1]), fmaxf(redA[2], redA[3])),
                   fmaxf(redA[4], redA[5]));
  float e = expf(sim - gm);
  float sm = wave_sum64(e);
  if (lane == 0) redB[wv] = sm;
  __syncthreads();
  float tot = redB[0] + redB[1] + redB[2] + redB[3] + redB[4] + redB[5];
  float w = e / tot;
  attnL[t] = w;

  float a8[8] = { w * e0.x, w * e0.y, w * e0.z, w * e0.w,
                  w * e1.x, w * e1.y, w * e1.z, w * e1.w };
#pragma unroll
  for (int cc = 0; cc < 8; ++cc){
    float r = wave_sum64(a8[cc]);
    if (lane == 0) red8[wv][cc] = r;
  }
  __syncthreads();
  if (t < 8){
    float sa = 0.f;
#pragma unroll
    for (int g = 0; g < 6; ++g) sa += red8[g][t];
    aws[t] = sa;
  }
  __syncthreads();

  {
    int dd = lane;
    const float* vp = vb_ + h * 64 + dd;
    int j0 = wv * 64;
    float va = 0.f, vb2 = 0.f;
#pragma unroll 8
    for (int jj = 0; jj < 64; jj += 2){
      va  = fmaf(attnL[j0 + jj],     vp[(size_t)(j0 + jj) * 256],     va);
      vb2 = fmaf(attnL[j0 + jj + 1], vp[(size_t)(j0 + jj + 1) * 256], vb2);
    }
    part[t] = va + vb2;
  }
  __syncthreads();
  if (t < 64){
    float o = part[t] + part[64 + t] + part[128 + t] + part[192 + t]
            + part[256 + t] + part[320 + t];
    float ew = 0.f;
#pragma unroll
    for (int cc = 0; cc < 8; ++cc) ew = fmaf(aws[cc], We[cc * 256 + h * 64 + t], ew);
    o += ew + be[h * 64 + t];
    aout[i * 256 + h * 64 + t] = o;
  }
}

// proj (8-way K-split, float4) + gate_a + LN2. One row/block, 256 thr.
// Outputs: snx2buf (LN2'd row), xrowB (post-gate residual row).
__global__ __launch_bounds__(256) void k_projgate(
    const float* __restrict__ aout,
    const float* __restrict__ Wo, const float* __restrict__ bo,
    const float* __restrict__ Wg_a,
    const float* __restrict__ ln2s, const float* __restrict__ ln2b,
    const float* __restrict__ xin,
    float* __restrict__ snx2buf, float* __restrict__ xrowB)
{
  __shared__ float ain[256];
  __shared__ float xo[128];
  __shared__ float orow[128];
  __shared__ float xrow[128];
  __shared__ float4 pr[256];
  __shared__ float red[4];

  int i = swz_row(blockIdx.x);
  int t = threadIdx.x;

  ain[t] = aout[(size_t)i * 256 + t];
  if (t < 128) xo[t] = xin[(size_t)i * 128 + t];
  __syncthreads();

  {
    int cq = t & 31, ks = t >> 5;      // 32 col-quads x 8 K-subranges(32 each)
    const float4* Wo4 = (const float4*)Wo;  // [256][32]
    float4 acc = {0.f, 0.f, 0.f, 0.f};
#pragma unroll
    for (int kk = 0; kk < 32; ++kk){
      int k = ks * 32 + kk;
      float4 w = Wo4[(size_t)k * 32 + cq];
      float a = ain[k];
      acc.x = fmaf(a, w.x, acc.x); acc.y = fmaf(a, w.y, acc.y);
      acc.z = fmaf(a, w.z, acc.z); acc.w = fmaf(a, w.w, acc.w);
    }
    pr[ks * 32 + cq] = acc;
  }
  __syncthreads();
  if (t < 32){
    float4 s = pr[t];
#pragma unroll
    for (int s3 = 1; s3 < 8; ++s3){
      float4 p = pr[s3 * 32 + t];
      s.x += p.x; s.y += p.y; s.z += p.z; s.w += p.w;
    }
    float4 b = ((const float4*)bo)[t];
    s.x += b.x; s.y += b.y; s.z += b.z; s.w += b.w;
    ((float4*)orow)[t] = s;
  }
  __syncthreads();

  if (t < 128){
    float o = orow[t], xov = xo[t];
    float gp = o * Wg_a[t] + xov * Wg_a[128 + t] + (o - xov) * Wg_a[256 + t];
    float sg = wave_sum64(gp);
    if (t == 0)  red[0] = sg;
    if (t == 64) red[1] = sg;
  }
  __syncthreads();
  if (t < 128){
    float z = red[0] + red[1];
    float gg = 1.0f / (1.0f + expf(-z));
    float xr = orow[t] * gg + xo[t] * (1.0f - gg);
    xrow[t] = xr;
    xrowB[(size_t)i * 128 + t] = xr;
    float s = wave_sum64(xr);
    if (t == 0)  red[2] = s;
    if (t == 64) red[3] = s;
  }
  __syncthreads();
  if (t < 128){
    float mu = (red[2] + red[3]) * (1.0f / 128.0f);
    float dc = xrow[t] - mu;
    float s2 = wave_sum64(dc * dc);
    if (t == 0)  red[0] = s2;
    if (t == 64) red[1] = s2;
    __syncthreads();
    float var = (red[0] + red[1]) * (1.0f / 128.0f);
    float rstd = 1.0f / sqrtf(var + 1e-3f);
    snx2buf[(size_t)i * 128 + t] = dc * rstd * ln2s[t] + ln2b[t];
  } else {
    __syncthreads();
  }
}

// FFN1 + GELU. Grid 768 = (row, chunk of 256 cols). 256 thr: col-pair x 2 K-halves.
__global__ __launch_bounds__(256) void k_ffn1(
    const float* __restrict__ snx2buf,
    const float* __restrict__ W1, const float* __restrict__ b1,
    float* __restrict__ hbuf)
{
  __shared__ float sx[128];
  __shared__ float2 pr2[128];
  int id = blockIdx.x;           // 768 = 8 xcd * (48 rows * 2 chunks)
  int xcd = id & 7, loc = id >> 3;
  int i = xcd * 48 + (loc >> 1);
  int ch = loc & 1;
  int t = threadIdx.x;

  if (t < 128) sx[t] = snx2buf[(size_t)i * 128 + t];
  __syncthreads();

  int cp = t & 127, ks = t >> 7;
  int c2 = ch * 128 + cp;                    // float2 column index in [0,256)
  const float2* W12 = (const float2*)W1;     // [128][256]
  float a0 = 0.f, a1 = 0.f;
#pragma unroll 8
  for (int kk = 0; kk < 64; ++kk){
    int k = ks * 64 + kk;
    float2 w = W12[(size_t)k * 256 + c2];
    float x = sx[k];
    a0 = fmaf(x, w.x, a0); a1 = fmaf(x, w.y, a1);
  }
  if (ks == 1){ pr2[cp].x = a0; pr2[cp].y = a1; }
  __syncthreads();
  if (ks == 0){
    a0 += pr2[cp].x + b1[2 * c2];
    a1 += pr2[cp].y + b1[2 * c2 + 1];
    const float RS2 = 0.70710678118654752440f;
    float g0 = 0.5f * a0 * (1.0f + erff(a0 * RS2));
    float g1 = 0.5f * a1 * (1.0f + erff(a1 * RS2));
    float2 gv; gv.x = g0; gv.y = g1;
    ((float2*)hbuf)[(size_t)i * 256 + c2] = gv;
  }
}

// FFN2 (no gate). Grid 768 = (row, half of 64 cols). 256 thr: 16 quads x 16 K-subs.
__global__ __launch_bounds__(256) void k_ffn2(
    const float* __restrict__ hbuf,
    const float* __restrict__ W2, const float* __restrict__ b2,
    float* __restrict__ fbuf)
{
  __shared__ float hh[512];
  __shared__ float4 pr[256];
  int id = blockIdx.x;           // 768 = 8 xcd * (48 rows * 2 halves)
  int xcd = id & 7, loc = id >> 3;
  int i = xcd * 48 + (loc >> 1);
  int hc = loc & 1;
  int t = threadIdx.x;

  hh[t] = hbuf[(size_t)i * 512 + t];
  hh[256 + t] = hbuf[(size_t)i * 512 + 256 + t];
  __syncthreads();

  int q = t & 15, ks = t >> 4;               // 16 quads x 16 K-subs (32 k each)
  int gq = hc * 16 + q;                      // global quad in [0,32)
  const float4* W24 = (const float4*)W2;     // [512][32]
  float4 acc = {0.f, 0.f, 0.f, 0.f};
#pragma unroll
  for (int kk = 0; kk < 32; ++kk){
    int k = ks * 32 + kk;
    float4 w = W24[(size_t)k * 32 + gq];
    float a = hh[k];
    acc.x = fmaf(a, w.x, acc.x); acc.y = fmaf(a, w.y, acc.y);
    acc.z = fmaf(a, w.z, acc.z); acc.w = fmaf(a, w.w, acc.w);
  }
  pr[ks * 16 + q] = acc;
  __syncthreads();
  if (t < 16){
    float4 s = pr[t];
#pragma unroll
    for (int s3 = 1; s3 < 16; ++s3){
      float4 p = pr[s3 * 16 + t];
      s.x += p.x; s.y += p.y; s.z += p.z; s.w += p.w;
    }
    float4 b = ((const float4*)b2)[gq];
    s.x += b.x; s.y += b.y; s.z += b.z; s.w += b.w;
    ((float4*)fbuf)[(size_t)i * 32 + gq] = s;
  }
}

// gate_f + LN1(next) + one of {Q, K, V} GEMV. Grid 1152 = (row, part). 256 thr.
// part 0 also writes xnew -> xbuf and computes qWe/qbe.
__global__ __launch_bounds__(256) void k_qkv(
    const float* __restrict__ fbuf, const float* __restrict__ xrowB,
    const float* __restrict__ Wg_f,
    const float* __restrict__ ls_n, const float* __restrict__ lb_n,
    const float* __restrict__ Wq_n, const float* __restrict__ bq_n,
    const float* __restrict__ Wkv_n, const float* __restrict__ bkv_n,
    const float* __restrict__ We_n, const float* __restrict__ be_n,
    const float* __restrict__ cosS, const float* __restrict__ sinS,
    float* __restrict__ xbuf,
    float* __restrict__ qb_, float* __restrict__ kbT, float* __restrict__ vb_,
    float* __restrict__ qWeB, float* __restrict__ qbeB)
{
  __shared__ float snx[128];
  __shared__ float xnewL[128];
  __shared__ float2 qp2[128];
  __shared__ float red[4];

  int id = blockIdx.x;           // 1152 = 8 xcd * (48 rows * 3 parts)
  int xcd = id & 7, loc = id >> 3;
  int i = xcd * 48 + loc / 3;
  int part = loc % 3;
  int t = threadIdx.x;

  // ---- redundant gate_f + LN1' head (deterministic, identical across parts)
  float fv = 0.f, xr = 0.f;
  if (t < 128){
    fv = fbuf[(size_t)i * 128 + t];
    xr = xrowB[(size_t)i * 128 + t];
    float gp = fv * Wg_f[t] + xr * Wg_f[128 + t] + (fv - xr) * Wg_f[256 + t];
    float sg = wave_sum64(gp);
    if (t == 0)  red[0] = sg;
    if (t == 64) red[1] = sg;
  }
  __syncthreads();
  if (t < 128){
    float z = red[0] + red[1];
    float gg = 1.0f / (1.0f + expf(-z));
    float xn = fv * gg + xr * (1.0f - gg);
    xnewL[t] = xn;
    if (part == 0) xbuf[(size_t)i * 128 + t] = xn;
    float s = wave_sum64(xn);
    if (t == 0)  red[2] = s;
    if (t == 64) red[3] = s;
  }
  __syncthreads();
  if (t < 128){
    float mu = (red[2] + red[3]) * (1.0f / 128.0f);
    float dn = xnewL[t] - mu;
    float s2 = wave_sum64(dn * dn);
    if (t == 0)  red[0] = s2;
    if (t == 64) red[1] = s2;
    __syncthreads();
    float var = (red[0] + red[1]) * (1.0f / 128.0f);
    float rstd = 1.0f / sqrtf(var + 1e-3f);
    snx[t] = dn * rstd * ls_n[t] + lb_n[t];
  } else {
    __syncthreads();
  }
  __syncthreads();

  // ---- body: one of q/k/v. col-pair cp, 2-way K-split.
  int cp = t & 127, ks = t >> 7;
  const float2* Wp; const float* bb; int stride;
  if (part == 0)      { Wp = (const float2*)Wq_n + cp;        stride = 128; bb = bq_n; }
  else if (part == 1) { Wp = (const float2*)Wkv_n + cp;       stride = 256; bb = bkv_n; }
  else                { Wp = (const float2*)Wkv_n + 128 + cp; stride = 256; bb = bkv_n + 256; }

  float a0 = 0.f, a1 = 0.f;
#pragma unroll 8
  for (int kk = 0; kk < 64; ++kk){
    int k = ks * 64 + kk;
    float2 w = Wp[(size_t)k * stride];
    float x = snx[k];
    a0 = fmaf(x, w.x, a0); a1 = fmaf(x, w.y, a1);
  }
  if (ks == 1){ qp2[cp].x = a0; qp2[cp].y = a1; }
  __syncthreads();
  if (ks == 0){
    a0 += qp2[cp].x + bb[2 * cp];
    a1 += qp2[cp].y + bb[2 * cp + 1];
    if (part < 2){
      int dloc = (2 * cp) & 63;
      float c = cosS[i * 64 + dloc], s = sinS[i * 64 + dloc];
      float r0 = a0 * c - a1 * s;
      float r1 = a1 * c + a0 * s;
      if (part == 0){
        qb_[i * 256 + 2 * cp]     = r0;
        qb_[i * 256 + 2 * cp + 1] = r1;
        int h = cp >> 5;
#pragma unroll
        for (int cc = 0; cc < 8; ++cc){
          float pr = r0 * We_n[cc * 256 + 2 * cp] + r1 * We_n[cc * 256 + 2 * cp + 1];
#pragma unroll
          for (int m = 16; m >= 1; m >>= 1) pr += __shfl_xor(pr, m, 32);
          if ((t & 31) == 0) qWeB[(h * NTOK + i) * 8 + cc] = pr;
        }
        float pb = r0 * be_n[2 * cp] + r1 * be_n[2 * cp + 1];
#pragma unroll
        for (int m = 16; m >= 1; m >>= 1) pb += __shfl_xor(pb, m, 32);
        if ((t & 31) == 0) qbeB[h * NTOK + i] = pb;
      } else {
        int h = cp >> 5, d0 = 2 * (cp & 31);
        kbT[(size_t)(h * 64 + d0) * NTOK + i]     = r0;
        kbT[(size_t)(h * 64 + d0 + 1) * NTOK + i] = r1;
      }
    } else {
      vb_[i * 256 + 2 * cp]     = a0;
      vb_[i * 256 + 2 * cp + 1] = a1;
    }
  }
}

// Last-layer gate_f only. 384 blocks x 128 thr.
__global__ __launch_bounds__(128) void k_gatelast(
    const float* __restrict__ fbuf, const float* __restrict__ xrowB,
    const float* __restrict__ Wg_f, float* __restrict__ xbuf)
{
  __shared__ float red[2];
  int i = swz_row(blockIdx.x);
  int t = threadIdx.x;
  float fv = fbuf[(size_t)i * 128 + t];
  float xr = xrowB[(size_t)i * 128 + t];
  float gp = fv * Wg_f[t] + xr * Wg_f[128 + t] + (fv - xr) * Wg_f[256 + t];
  float sg = wave_sum64(gp);
  if (t == 0)  red[0] = sg;
  if (t == 64) red[1] = sg;
  __syncthreads();
  float z = red[0] + red[1];
  float gg = 1.0f / (1.0f + expf(-z));
  xbuf[(size_t)i * 128 + t] = fv * gg + xr * (1.0f - gg);
}

// Final head. Single block, 384 threads, float4 x loads.
__global__ __launch_bounds__(384) void k_final(
    const float* __restrict__ x,
    const float* __restrict__ Wd1, const float* __restrict__ bd1,
    const float* __restrict__ Wd2, const float* __restrict__ bd2,
    float* __restrict__ out)
{
  __shared__ float red[6];
  int i = threadIdx.x;
  float y[9];
#pragma unroll
  for (int c = 0; c < 9; ++c) y[c] = bd1[c];
  const float4* x4 = (const float4*)(x + (size_t)i * 128);
#pragma unroll 8
  for (int r4 = 0; r4 < 32; ++r4){
    float4 xv = x4[r4];
    const float* wp = Wd1 + (r4 * 4) * 9;
#pragma unroll
    for (int c = 0; c < 9; ++c) y[c] = fmaf(xv.x, wp[c], y[c]);
#pragma unroll
    for (int c = 0; c < 9; ++c) y[c] = fmaf(xv.y, wp[9 + c], y[c]);
#pragma unroll
    for (int c = 0; c < 9; ++c) y[c] = fmaf(xv.z, wp[18 + c], y[c]);
#pragma unroll
    for (int c = 0; c < 9; ++c) y[c] = fmaf(xv.w, wp[27 + c], y[c]);
  }
#pragma unroll
  for (int c = 0; c < 9; ++c) y[c] = fmaxf(y[c], 0.0f);
  float z[3];
#pragma unroll
  for (int c = 0; c < 3; ++c){
    float a = bd2[c];
#pragma unroll
    for (int r = 0; r < 9; ++r) a = fmaf(y[r], Wd2[r * 3 + c], a);
    z[c] = a;
  }
#pragma unroll
  for (int c = 0; c < 3; ++c){
    float s = wave_sum64(z[c]);
    if ((i & 63) == 0) red[i >> 6] = s;
    __syncthreads();
    float tot = 0.f;
#pragma unroll
    for (int w = 0; w < 6; ++w) tot += red[w];
    float mean = tot * (1.0f / 384.0f);
    out[i * 3 + c] = z[c] - mean;
    __syncthreads();
  }
}

extern "C" void kernel_launch(void* const* d_in, const int* in_sizes, int n_in,
                              void* d_out, int out_size, void* d_ws, size_t ws_size,
                              hipStream_t stream)
{
  const float* nodes   = (const float*)d_in[0];
  const float* edges   = (const float*)d_in[1];
  const float* ln1_s   = (const float*)d_in[2];
  const float* ln1_b   = (const float*)d_in[3];
  const float* Wq      = (const float*)d_in[4];
  const float* bq      = (const float*)d_in[5];
  const float* Wkv     = (const float*)d_in[6];
  const float* bkv     = (const float*)d_in[7];
  const float* We      = (const float*)d_in[8];
  const float* be      = (const float*)d_in[9];
  const float* Wo      = (const float*)d_in[10];
  const float* bo      = (const float*)d_in[11];
  const float* Wg_attn = (const float*)d_in[12];
  const float* ln2_s   = (const float*)d_in[13];
  const float* ln2_b   = (const float*)d_in[14];
  const float* W1      = (const float*)d_in[15];
  const float* b1      = (const float*)d_in[16];
  const float* W2      = (const float*)d_in[17];
  const float* b2      = (const float*)d_in[18];
  const float* Wg_ff   = (const float*)d_in[19];
  const float* Wd1     = (const float*)d_in[20];
  const float* bd1     = (const float*)d_in[21];
  const float* Wd2     = (const float*)d_in[22];
  const float* bd2     = (const float*)d_in[23];
  // d_in[24] = mask: all-true; no-op in the math.

  float* ws    = (float*)d_ws;
  float* cosS  = ws;                  // 384*64
  float* sinS  = cosS + 24576;
  float* qbuf  = sinS + 24576;        // 384*256
  float* kbT   = qbuf + 98304;        // [4][64][384]
  float* vbuf  = kbT + 98304;
  float* qWeB  = vbuf + 98304;        // 4*384*8
  float* qbeB  = qWeB + 12288;        // 4*384
  float* aoutB = qbeB + 1536;         // 384*256
  float* xbuf  = aoutB + 98304;       // 384*128
  float* snx2B = xbuf + 49152;        // 384*128
  float* xrowB = snx2B + 49152;       // 384*128
  float* fbuf  = xrowB + 49152;       // 384*128
  float* hbuf  = fbuf + 49152;        // 384*512

  k_lnqkv<<<dim3(NTOK), dim3(512), 0, stream>>>(
      nodes, ln1_s, ln1_b, Wq, bq, Wkv, bkv, We, be,
      cosS, sinS, qbuf, kbT, vbuf, qWeB, qbeB);

  for (int L = 0; L < DEPTH; ++L){
    k_attn<<<dim3(NTOK * HEADS), dim3(384), 0, stream>>>(
        qbuf, kbT, vbuf, qWeB, qbeB, edges,
        We + (size_t)L * EDGE * INNER, be + L * INNER, aoutB);
    k_projgate<<<dim3(NTOK), dim3(256), 0, stream>>>(
        aoutB, Wo + (size_t)L * INNER * DIM, bo + L * DIM,
        Wg_attn + L * 3 * DIM, ln2_s + L * DIM, ln2_b + L * DIM,
        (L == 0) ? nodes : xbuf, snx2B, xrowB);
    k_ffn1<<<dim3(NTOK * 2), dim3(256), 0, stream>>>(
        snx2B, W1 + (size_t)L * DIM * FFD, b1 + L * FFD, hbuf);
    k_ffn2<<<dim3(NTOK * 2), dim3(256), 0, stream>>>(
        hbuf, W2 + (size_t)L * FFD * DIM, b2 + L * DIM, fbuf);
    if (L < DEPTH - 1){
      int Ln = L + 1;
      k_qkv<<<dim3(NTOK * 3), dim3(256), 0, stream>>>(
          fbuf, xrowB, Wg_ff + L * 3 * DIM,
          ln1_s + Ln * DIM, ln1_b + Ln * DIM,
          Wq + (size_t)Ln * DIM * INNER, bq + Ln * INNER,
          Wkv + (size_t)Ln * DIM * 2 * INNER, bkv + Ln * 2 * INNER,
          We + (size_t)Ln * EDGE * INNER, be + Ln * INNER,
          cosS, sinS, xbuf, qbuf, kbT, vbuf, qWeB, qbeB);
    } else {
      k_gatelast<<<dim3(NTOK), dim3(128), 0, stream>>>(
          fbuf, xrowB, Wg_ff + L * 3 * DIM, xbuf);
    }
  }

  k_final<<<dim3(1), dim3(384), 0, stream>>>(xbuf, Wd1, bd1, Wd2, bd2, (float*)d_out);
}

// Round 9
// 138.003 us; speedup vs baseline: 1.2616x; 1.2616x over previous
//
#include <hip/hip_runtime.h>
#include <math.h>

#define NTOK 384
#define DIM  128
#define HEADS 4
#define DHEAD 64
#define INNER 256
#define DEPTH 3
#define EDGE 8
#define FFD 512

__device__ __forceinline__ float wave_sum64(float v){
#pragma unroll
  for (int m = 32; m >= 1; m >>= 1) v += __shfl_xor(v, m, 64);
  return v;
}
__device__ __forceinline__ float wave_max64(float v){
#pragma unroll
  for (int m = 32; m >= 1; m >>= 1) v = fmaxf(v, __shfl_xor(v, m, 64));
  return v;
}

// XCD-pinned row mapping: 384 = 8 XCDs x 48 rows.
__device__ __forceinline__ int swz_row(int id){ return (id & 7) * 48 + (id >> 3); }

// Rotary for one (i, d): numpy float32 semantics via double precision then round.
__device__ __forceinline__ void rotary_val(int i, int d, float* c, float* s){
  int j = d >> 1;
  double ex = (double)(2 * j) / 64.0;
  float p = (float)pow(10000.0, ex);
  float inv = 1.0f / p;
  float f = (float)i * inv;
  double fd = (double)f;
  *c = (float)cos(fd);
  *s = (float)sin(fd);
}

// QKV (+rotary, qWe, qbe) for ONE row. Block >= 512 threads.
// Thread layout: t<192 -> (quad=t, ks=0); 192<=t<384 -> (quad=t-192, ks=1).
// quad 0-63: q cols 4quad; 64-127: k cols 4(quad-64); 128-191: v cols 4(quad-128).
// float4 weight loads, K split in two 64-halves, LDS combine, epilogue on ks=0.
// Contains 1 barrier (all threads reach it).
__device__ __forceinline__ void qkv_row_v2(
    int i, int t, const float* __restrict__ snx,
    const float* __restrict__ Wq, const float* __restrict__ bq,
    const float* __restrict__ Wkv, const float* __restrict__ bkv,
    const float* __restrict__ We, const float* __restrict__ be,
    const float* __restrict__ cosRow, const float* __restrict__ sinRow,
    float* __restrict__ qb_, float* __restrict__ kbT, float* __restrict__ vb_,
    float* __restrict__ qWeB, float* __restrict__ qbeB,
    float4* __restrict__ qp4)     // LDS, 192 float4
{
  int ks   = (t < 192) ? 0 : 1;
  int quad = (t < 192) ? t : t - 192;
  float4 acc = {0.f, 0.f, 0.f, 0.f};
  if (t < 384){
    const float4* Wp; int stride4;
    if (quad < 64){ Wp = (const float4*)Wq + quad;        stride4 = 64;  }
    else          { Wp = (const float4*)Wkv + (quad - 64); stride4 = 128; }
    int k0 = ks * 64;
#pragma unroll 8
    for (int kk = 0; kk < 64; ++kk){
      int k = k0 + kk;
      float4 w = Wp[(size_t)k * stride4];
      float x = snx[k];
      acc.x = fmaf(x, w.x, acc.x); acc.y = fmaf(x, w.y, acc.y);
      acc.z = fmaf(x, w.z, acc.z); acc.w = fmaf(x, w.w, acc.w);
    }
    if (ks == 1) qp4[quad] = acc;
  }
  __syncthreads();
  if (t < 192){
    float4 p = qp4[quad];
    acc.x += p.x; acc.y += p.y; acc.z += p.z; acc.w += p.w;
    if (quad < 64){
      // ---- Q quad: cols c0..c0+3
      int c0 = 4 * quad;
      float4 b = ((const float4*)bq)[quad];
      float a0 = acc.x + b.x, a1 = acc.y + b.y, a2 = acc.z + b.z, a3 = acc.w + b.w;
      int d0 = c0 & 63;
      float c_0 = cosRow[d0],     s_0 = sinRow[d0];
      float c_1 = cosRow[d0 + 2], s_1 = sinRow[d0 + 2];
      float r0 = a0 * c_0 - a1 * s_0;
      float r1 = a1 * c_0 + a0 * s_0;
      float r2 = a2 * c_1 - a3 * s_1;
      float r3 = a3 * c_1 + a2 * s_1;
      float4 qv; qv.x = r0; qv.y = r1; qv.z = r2; qv.w = r3;
      *(float4*)(qb_ + (size_t)i * 256 + c0) = qv;
      int h = quad >> 4;        // lanes 16h..16h+15 hold head h (t<64 = wave 0)
#pragma unroll
      for (int cc = 0; cc < 8; ++cc){
        const float* wc = We + cc * 256 + c0;
        float pr = r0 * wc[0] + r1 * wc[1] + r2 * wc[2] + r3 * wc[3];
#pragma unroll
        for (int m = 8; m >= 1; m >>= 1) pr += __shfl_xor(pr, m, 16);
        if ((t & 15) == 0) qWeB[(h * NTOK + i) * 8 + cc] = pr;
      }
      const float* bc = be + c0;
      float pb = r0 * bc[0] + r1 * bc[1] + r2 * bc[2] + r3 * bc[3];
#pragma unroll
      for (int m = 8; m >= 1; m >>= 1) pb += __shfl_xor(pb, m, 16);
      if ((t & 15) == 0) qbeB[h * NTOK + i] = pb;
    } else if (quad < 128){
      // ---- K quad: cols c0..c0+3 of K, written transposed kbT[h][d][j]
      int c0 = 4 * (quad - 64);
      float4 b = ((const float4*)bkv)[quad - 64];
      float a0 = acc.x + b.x, a1 = acc.y + b.y, a2 = acc.z + b.z, a3 = acc.w + b.w;
      int d0 = c0 & 63, h = c0 >> 6;
      float c_0 = cosRow[d0],     s_0 = sinRow[d0];
      float c_1 = cosRow[d0 + 2], s_1 = sinRow[d0 + 2];
      float r0 = a0 * c_0 - a1 * s_0;
      float r1 = a1 * c_0 + a0 * s_0;
      float r2 = a2 * c_1 - a3 * s_1;
      float r3 = a3 * c_1 + a2 * s_1;
      float* kp = kbT + (size_t)(h * 64 + d0) * NTOK + i;
      kp[0]        = r0;
      kp[NTOK]     = r1;
      kp[2 * NTOK] = r2;
      kp[3 * NTOK] = r3;
    } else {
      // ---- V quad: cols c0..c0+3
      int vq = quad - 128;
      int c0 = 4 * vq;
      float4 b = ((const float4*)bkv)[64 + vq];
      float4 vv;
      vv.x = acc.x + b.x; vv.y = acc.y + b.y;
      vv.z = acc.z + b.z; vv.w = acc.w + b.w;
      *(float4*)(vb_ + (size_t)i * 256 + c0) = vv;
    }
  }
}

// Layer-0: rotary (own row, into LDS + global table) + LN1 + QKV. 512 thr/row.
__global__ __launch_bounds__(512) void k_lnqkv(
    const float* __restrict__ x,
    const float* __restrict__ ls, const float* __restrict__ lb,
    const float* __restrict__ Wq, const float* __restrict__ bq,
    const float* __restrict__ Wkv, const float* __restrict__ bkv,
    const float* __restrict__ We, const float* __restrict__ be,
    float* __restrict__ cosS, float* __restrict__ sinS,
    float* __restrict__ qb_, float* __restrict__ kbT, float* __restrict__ vb_,
    float* __restrict__ qWeB, float* __restrict__ qbeB)
{
  __shared__ float snx[128];
  __shared__ float crow[64], srow[64];
  __shared__ float red[4];
  __shared__ float4 qp4[192];
  int i = swz_row(blockIdx.x);
  int t = threadIdx.x;

  if (t >= 448){
    int d = t - 448;
    float c, s;
    rotary_val(i, d, &c, &s);
    crow[d] = c; srow[d] = s;
    cosS[i * 64 + d] = c; sinS[i * 64 + d] = s;
  }
  float xv = (t < 128) ? x[(size_t)i * 128 + t] : 0.f;
  float s = (t < 128) ? wave_sum64(xv) : 0.f;
  if (t == 0)  red[0] = s;
  if (t == 64) red[1] = s;
  __syncthreads();
  float mu = (red[0] + red[1]) * (1.0f / 128.0f);
  float d = xv - mu;
  float s2 = (t < 128) ? wave_sum64(d * d) : 0.f;
  if (t == 0)  red[2] = s2;
  if (t == 64) red[3] = s2;
  __syncthreads();
  if (t < 128){
    float var = (red[2] + red[3]) * (1.0f / 128.0f);
    float rstd = 1.0f / sqrtf(var + 1e-3f);
    snx[t] = d * rstd * ls[t] + lb[t];
  }
  __syncthreads();
  qkv_row_v2(i, t, snx, Wq, bq, Wkv, bkv, We, be, crow, srow,
             qb_, kbT, vb_, qWeB, qbeB, qp4);
}

// Attention for one (i, h). 384 threads, thread t <-> j=t. K is transposed.
__global__ __launch_bounds__(384) void k_attn(
    const float* __restrict__ qb_, const float* __restrict__ kbT, const float* __restrict__ vb_,
    const float* __restrict__ qWeB, const float* __restrict__ qbeB,
    const float* __restrict__ edges,
    const float* __restrict__ We, const float* __restrict__ be,
    float* __restrict__ aout)
{
  __shared__ float qs[64];
  __shared__ float qw[8];
  __shared__ float qbs_s;
  __shared__ float attnL[NTOK];
  __shared__ float redA[6], redB[6];
  __shared__ float red8[6][8];
  __shared__ float aws[8];
  __shared__ float part[NTOK];

  int id = blockIdx.x;           // 1536 = 8 xcd * (48 rows * 4 heads)
  int xcd = id & 7, loc = id >> 3;
  int i = xcd * 48 + (loc % 48);
  int h = loc / 48;
  int t = threadIdx.x, lane = t & 63, wv = t >> 6;

  if (t < 64) qs[t] = qb_[i * 256 + h * 64 + t];
  else if (t < 72) qw[t - 64] = qWeB[(h * NTOK + i) * 8 + (t - 64)];
  else if (t == 72) qbs_s = qbeB[h * NTOK + i];
  __syncthreads();

  const float* kTp = kbT + (size_t)(h * 64) * NTOK + t;
  float ac0 = 0.f, ac1 = 0.f, ac2 = 0.f, ac3 = 0.f;
#pragma unroll 8
  for (int d = 0; d < 64; d += 4){
    ac0 = fmaf(qs[d],     kTp[(size_t)d * NTOK],       ac0);
    ac1 = fmaf(qs[d + 1], kTp[(size_t)(d + 1) * NTOK], ac1);
    ac2 = fmaf(qs[d + 2], kTp[(size_t)(d + 2) * NTOK], ac2);
    ac3 = fmaf(qs[d + 3], kTp[(size_t)(d + 3) * NTOK], ac3);
  }
  const float* ep = edges + ((size_t)i * NTOK + t) * 8;
  float4 e0 = *(const float4*)ep;
  float4 e1 = *(const float4*)(ep + 4);
  float ed = e0.x * qw[0] + e0.y * qw[1] + e0.z * qw[2] + e0.w * qw[3]
           + e1.x * qw[4] + e1.y * qw[5] + e1.z * qw[6] + e1.w * qw[7];
  float sim = 0.125f * (ac0 + ac1 + ac2 + ac3 + ed + qbs_s);

  float mx = wave_max64(sim);
  if (lane == 0) redA[wv] = mx;
  __syncthreads();
  float gm = fmaxf(fmaxf(fmaxf(redA[0], redA[1]), fmaxf(redA[2], redA[3])),
                   fmaxf(redA[4], redA[5]));
  float e = expf(sim - gm);
  float sm = wave_sum64(e);
  if (lane == 0) redB[wv] = sm;
  __syncthreads();
  float tot = redB[0] + redB[1] + redB[2] + redB[3] + redB[4] + redB[5];
  float w = e / tot;
  attnL[t] = w;

  float a8[8] = { w * e0.x, w * e0.y, w * e0.z, w * e0.w,
                  w * e1.x, w * e1.y, w * e1.z, w * e1.w };
#pragma unroll
  for (int cc = 0; cc < 8; ++cc){
    float r = wave_sum64(a8[cc]);
    if (lane == 0) red8[wv][cc] = r;
  }
  __syncthreads();
  if (t < 8){
    float sa = 0.f;
#pragma unroll
    for (int g = 0; g < 6; ++g) sa += red8[g][t];
    aws[t] = sa;
  }
  __syncthreads();

  {
    int dd = lane;
    const float* vp = vb_ + h * 64 + dd;
    int j0 = wv * 64;
    float va = 0.f, vb2 = 0.f;
#pragma unroll 8
    for (int jj = 0; jj < 64; jj += 2){
      va  = fmaf(attnL[j0 + jj],     vp[(size_t)(j0 + jj) * 256],     va);
      vb2 = fmaf(attnL[j0 + jj + 1], vp[(size_t)(j0 + jj + 1) * 256], vb2);
    }
    part[t] = va + vb2;
  }
  __syncthreads();
  if (t < 64){
    float o = part[t] + part[64 + t] + part[128 + t] + part[192 + t]
            + part[256 + t] + part[320 + t];
    float ew = 0.f;
#pragma unroll
    for (int cc = 0; cc < 8; ++cc) ew = fmaf(aws[cc], We[cc * 256 + h * 64 + t], ew);
    o += ew + be[h * 64 + t];
    aout[i * 256 + h * 64 + t] = o;
  }
}

// Fused tail: proj+gate+LN2+FFN+gate (+next-layer LN1+QKV). One row/block, 512 thr.
__global__ __launch_bounds__(512) void k_tail(
    const float* __restrict__ aout,
    const float* __restrict__ Wo, const float* __restrict__ bo,
    const float* __restrict__ Wg_a,
    const float* __restrict__ ln2s, const float* __restrict__ ln2b,
    const float* __restrict__ W1, const float* __restrict__ b1,
    const float* __restrict__ W2, const float* __restrict__ b2,
    const float* __restrict__ Wg_f,
    const float* __restrict__ xin, float* __restrict__ xout,
    int has_next,
    const float* __restrict__ ls_n, const float* __restrict__ lb_n,
    const float* __restrict__ Wq_n, const float* __restrict__ bq_n,
    const float* __restrict__ Wkv_n, const float* __restrict__ bkv_n,
    const float* __restrict__ We_n, const float* __restrict__ be_n,
    const float* __restrict__ cosS, const float* __restrict__ sinS,
    float* __restrict__ qb_, float* __restrict__ kbT, float* __restrict__ vb_,
    float* __restrict__ qWeB, float* __restrict__ qbeB)
{
  __shared__ float ar[256];
  __shared__ float xold[128];
  __shared__ float xrow[128];
  __shared__ float snx[128];
  __shared__ float hs[512];
  __shared__ float4 prL[512];          // K-split partials; reused as qp4 in QKV phase
  __shared__ float red[4];
  float* prF = (float*)prL;

  int i = swz_row(blockIdx.x);
  int t = threadIdx.x;

  if (t < 64)            ((float4*)ar)[t]        = ((const float4*)(aout + (size_t)i * 256))[t];
  else if (t < 96)       ((float4*)xold)[t - 64] = ((const float4*)(xin + (size_t)i * 128))[t - 64];
  __syncthreads();

  // ---- proj: 128 outs, K=256. 32 colq x 16 ksub (16 k each).
  {
    int colq = t & 31, ksub = t >> 5;
    const float4* Wo4 = (const float4*)Wo;   // 32 float4 per row
    float4 acc = {0.f, 0.f, 0.f, 0.f};
#pragma unroll
    for (int kk = 0; kk < 16; ++kk){
      int k = ksub * 16 + kk;
      float4 w = Wo4[(size_t)k * 32 + colq];
      float a = ar[k];
      acc.x = fmaf(a, w.x, acc.x); acc.y = fmaf(a, w.y, acc.y);
      acc.z = fmaf(a, w.z, acc.z); acc.w = fmaf(a, w.w, acc.w);
    }
    prL[ksub * 32 + colq] = acc;
  }
  __syncthreads();

  // ---- reduce + gate_a + LN2 (2 waves)
  float o = 0.f;
  if (t < 128){
    o = bo[t];
#pragma unroll
    for (int s = 0; s < 16; ++s) o += prF[s * 128 + t];
    float xo = xold[t];
    float gp = o * Wg_a[t] + xo * Wg_a[128 + t] + (o - xo) * Wg_a[256 + t];
    float sg = wave_sum64(gp);
    if (t == 0)  red[0] = sg;
    if (t == 64) red[1] = sg;
  }
  __syncthreads();
  if (t < 128){
    float z = red[0] + red[1];
    float gg = 1.0f / (1.0f + expf(-z));
    xrow[t] = o * gg + xold[t] * (1.0f - gg);
  }
  __syncthreads();
  float xv2 = (t < 128) ? xrow[t] : 0.f;
  float s = (t < 128) ? wave_sum64(xv2) : 0.f;
  if (t == 0)  red[0] = s;
  if (t == 64) red[1] = s;
  __syncthreads();
  float mu = (red[0] + red[1]) * (1.0f / 128.0f);
  float dcen = xv2 - mu;
  float s2 = (t < 128) ? wave_sum64(dcen * dcen) : 0.f;
  if (t == 0)  red[2] = s2;
  if (t == 64) red[3] = s2;
  __syncthreads();
  if (t < 128){
    float var = (red[2] + red[3]) * (1.0f / 128.0f);
    float rstd = 1.0f / sqrtf(var + 1e-3f);
    snx[t] = dcen * rstd * ln2s[t] + ln2b[t];
  }
  __syncthreads();

  // ---- FFN1: 512 outs, K=128. 128 colq x 4 ksub (32 k each).
  {
    int colq = t & 127, ksub = t >> 7;
    const float4* W14 = (const float4*)W1;   // 128 float4 per row
    float4 acc = {0.f, 0.f, 0.f, 0.f};
#pragma unroll 8
    for (int kk = 0; kk < 32; ++kk){
      int k = ksub * 32 + kk;
      float4 w = W14[(size_t)k * 128 + colq];
      float a = snx[k];
      acc.x = fmaf(a, w.x, acc.x); acc.y = fmaf(a, w.y, acc.y);
      acc.z = fmaf(a, w.z, acc.z); acc.w = fmaf(a, w.w, acc.w);
    }
    prL[ksub * 128 + colq] = acc;
  }
  __syncthreads();

  // ---- reduce + GELU -> hs (512 threads, one col each)
  {
    float h = b1[t];
#pragma unroll
    for (int s3 = 0; s3 < 4; ++s3) h += prF[s3 * 512 + t];
    const float RS2 = 0.70710678118654752440f;
    hs[t] = 0.5f * h * (1.0f + erff(h * RS2));
  }
  __syncthreads();

  // ---- FFN2: 128 outs, K=512. 32 colq x 16 ksub (32 k each).
  {
    int colq = t & 31, ksub = t >> 5;
    const float4* W24 = (const float4*)W2;   // 32 float4 per row
    float4 acc = {0.f, 0.f, 0.f, 0.f};
#pragma unroll 8
    for (int kk = 0; kk < 32; ++kk){
      int k = ksub * 32 + kk;
      float4 w = W24[(size_t)k * 32 + colq];
      float a = hs[k];
      acc.x = fmaf(a, w.x, acc.x); acc.y = fmaf(a, w.y, acc.y);
      acc.z = fmaf(a, w.z, acc.z); acc.w = fmaf(a, w.w, acc.w);
    }
    prL[ksub * 32 + colq] = acc;
  }
  __syncthreads();

  // ---- reduce + gate_f + write xnew + next-layer LN1 (2 waves)
  float f = 0.f;
  if (t < 128){
    f = b2[t];
#pragma unroll
    for (int s3 = 0; s3 < 16; ++s3) f += prF[s3 * 128 + t];
    float xr = xrow[t];
    float gp = f * Wg_f[t] + xr * Wg_f[128 + t] + (f - xr) * Wg_f[256 + t];
    float sg = wave_sum64(gp);
    if (t == 0)  red[0] = sg;
    if (t == 64) red[1] = sg;
  }
  __syncthreads();
  float xnew = 0.f;
  if (t < 128){
    float z = red[0] + red[1];
    float gg = 1.0f / (1.0f + expf(-z));
    xnew = f * gg + xrow[t] * (1.0f - gg);
    xout[(size_t)i * 128 + t] = xnew;
  }
  if (has_next){
    float sn = (t < 128) ? wave_sum64(xnew) : 0.f;
    if (t == 0)  red[0] = sn;
    if (t == 64) red[1] = sn;
    __syncthreads();
    float mun = (red[0] + red[1]) * (1.0f / 128.0f);
    float dn = xnew - mun;
    float sn2 = (t < 128) ? wave_sum64(dn * dn) : 0.f;
    if (t == 0)  red[2] = sn2;
    if (t == 64) red[3] = sn2;
    __syncthreads();
    if (t < 128){
      float var = (red[2] + red[3]) * (1.0f / 128.0f);
      float rstd = 1.0f / sqrtf(var + 1e-3f);
      snx[t] = dn * rstd * ls_n[t] + lb_n[t];
    }
    __syncthreads();
    qkv_row_v2(i, t, snx, Wq_n, bq_n, Wkv_n, bkv_n, We_n, be_n,
               cosS + (size_t)i * 64, sinS + (size_t)i * 64,
               qb_, kbT, vb_, qWeB, qbeB, prL);
  }
}

// Final head. Single block, 384 threads, float4 x loads.
__global__ __launch_bounds__(384) void k_final(
    const float* __restrict__ x,
    const float* __restrict__ Wd1, const float* __restrict__ bd1,
    const float* __restrict__ Wd2, const float* __restrict__ bd2,
    float* __restrict__ out)
{
  __shared__ float red[6];
  int i = threadIdx.x;
  float y[9];
#pragma unroll
  for (int c = 0; c < 9; ++c) y[c] = bd1[c];
  const float4* x4 = (const float4*)(x + (size_t)i * 128);
#pragma unroll 8
  for (int r4 = 0; r4 < 32; ++r4){
    float4 xv = x4[r4];
    const float* wp = Wd1 + (r4 * 4) * 9;
#pragma unroll
    for (int c = 0; c < 9; ++c) y[c] = fmaf(xv.x, wp[c], y[c]);
#pragma unroll
    for (int c = 0; c < 9; ++c) y[c] = fmaf(xv.y, wp[9 + c], y[c]);
#pragma unroll
    for (int c = 0; c < 9; ++c) y[c] = fmaf(xv.z, wp[18 + c], y[c]);
#pragma unroll
    for (int c = 0; c < 9; ++c) y[c] = fmaf(xv.w, wp[27 + c], y[c]);
  }
#pragma unroll
  for (int c = 0; c < 9; ++c) y[c] = fmaxf(y[c], 0.0f);
  float z[3];
#pragma unroll
  for (int c = 0; c < 3; ++c){
    float a = bd2[c];
#pragma unroll
    for (int r = 0; r < 9; ++r) a = fmaf(y[r], Wd2[r * 3 + c], a);
    z[c] = a;
  }
#pragma unroll
  for (int c = 0; c < 3; ++c){
    float s = wave_sum64(z[c]);
    if ((i & 63) == 0) red[i >> 6] = s;
    __syncthreads();
    float tot = 0.f;
#pragma unroll
    for (int w = 0; w < 6; ++w) tot += red[w];
    float mean = tot * (1.0f / 384.0f);
    out[i * 3 + c] = z[c] - mean;
    __syncthreads();
  }
}

extern "C" void kernel_launch(void* const* d_in, const int* in_sizes, int n_in,
                              void* d_out, int out_size, void* d_ws, size_t ws_size,
                              hipStream_t stream)
{
  const float* nodes   = (const float*)d_in[0];
  const float* edges   = (const float*)d_in[1];
  const float* ln1_s   = (const float*)d_in[2];
  const float* ln1_b   = (const float*)d_in[3];
  const float* Wq      = (const float*)d_in[4];
  const float* bq      = (const float*)d_in[5];
  const float* Wkv     = (const float*)d_in[6];
  const float* bkv     = (const float*)d_in[7];
  const float* We      = (const float*)d_in[8];
  const float* be      = (const float*)d_in[9];
  const float* Wo      = (const float*)d_in[10];
  const float* bo      = (const float*)d_in[11];
  const float* Wg_attn = (const float*)d_in[12];
  const float* ln2_s   = (const float*)d_in[13];
  const float* ln2_b   = (const float*)d_in[14];
  const float* W1      = (const float*)d_in[15];
  const float* b1      = (const float*)d_in[16];
  const float* W2      = (const float*)d_in[17];
  const float* b2      = (const float*)d_in[18];
  const float* Wg_ff   = (const float*)d_in[19];
  const float* Wd1     = (const float*)d_in[20];
  const float* bd1     = (const float*)d_in[21];
  const float* Wd2     = (const float*)d_in[22];
  const float* bd2     = (const float*)d_in[23];
  // d_in[24] = mask: all-true; no-op in the math.

  float* ws   = (float*)d_ws;
  float* cosS = ws;                 // 384*64
  float* sinS = cosS + 24576;
  float* qbuf = sinS + 24576;       // 384*256
  float* kbT  = qbuf + 98304;       // [4][64][384]
  float* vbuf = kbT + 98304;
  float* qWeB = vbuf + 98304;       // 4*384*8
  float* qbeB = qWeB + 12288;       // 4*384
  float* aoutB = qbeB + 1536;       // 384*256
  float* xbuf = aoutB + 98304;      // 384*128

  k_lnqkv<<<dim3(NTOK), dim3(512), 0, stream>>>(
      nodes, ln1_s, ln1_b, Wq, bq, Wkv, bkv, We, be,
      cosS, sinS, qbuf, kbT, vbuf, qWeB, qbeB);

  for (int L = 0; L < DEPTH; ++L){
    int Ln = (L < DEPTH - 1) ? (L + 1) : L;
    k_attn<<<dim3(NTOK * HEADS), dim3(384), 0, stream>>>(
        qbuf, kbT, vbuf, qWeB, qbeB, edges,
        We + (size_t)L * EDGE * INNER, be + L * INNER, aoutB);
    k_tail<<<dim3(NTOK), dim3(512), 0, stream>>>(
        aoutB, Wo + (size_t)L * INNER * DIM, bo + L * DIM,
        Wg_attn + L * 3 * DIM,
        ln2_s + L * DIM, ln2_b + L * DIM,
        W1 + (size_t)L * DIM * FFD, b1 + L * FFD,
        W2 + (size_t)L * FFD * DIM, b2 + L * DIM,
        Wg_ff + L * 3 * DIM,
        (L == 0) ? nodes : xbuf, xbuf,
        (L < DEPTH - 1) ? 1 : 0,
        ln1_s + Ln * DIM, ln1_b + Ln * DIM,
        Wq + (size_t)Ln * DIM * INNER, bq + Ln * INNER,
        Wkv + (size_t)Ln * DIM * 2 * INNER, bkv + Ln * 2 * INNER,
        We + (size_t)Ln * EDGE * INNER, be + Ln * INNER,
        cosS, sinS, qbuf, kbT, vbuf, qWeB, qbeB);
  }

  k_final<<<dim3(1), dim3(384), 0, stream>>>(xbuf, Wd1, bd1, Wd2, bd2, (float*)d_out);
}

// Round 10
// 135.335 us; speedup vs baseline: 1.2865x; 1.0197x over previous
//
#include <hip/hip_runtime.h>
#include <math.h>

#define NTOK 384
#define DIM  128
#define HEADS 4
#define DHEAD 64
#define INNER 256
#define DEPTH 3
#define EDGE 8
#define FFD 512

__device__ __forceinline__ float wave_sum64(float v){
#pragma unroll
  for (int m = 32; m >= 1; m >>= 1) v += __shfl_xor(v, m, 64);
  return v;
}
__device__ __forceinline__ float wave_max64(float v){
#pragma unroll
  for (int m = 32; m >= 1; m >>= 1) v = fmaxf(v, __shfl_xor(v, m, 64));
  return v;
}

// XCD-pinned row mapping: 384 = 8 XCDs x 48 rows.
__device__ __forceinline__ int swz_row(int id){ return (id & 7) * 48 + (id >> 3); }

// Rotary for one (i, d): numpy float32 semantics via double precision then round.
__device__ __forceinline__ void rotary_val(int i, int d, float* c, float* s){
  int j = d >> 1;
  double ex = (double)(2 * j) / 64.0;
  float p = (float)pow(10000.0, ex);
  float inv = 1.0f / p;
  float f = (float)i * inv;
  double fd = (double)f;
  *c = (float)cos(fd);
  *s = (float)sin(fd);
}

// QKV (+rotary, qWe, qbe) for ONE row. Block >= 512 threads.
// t<192 -> (quad=t, ks=0); 192<=t<384 -> (quad=t-192, ks=1).
// quad 0-63: q col-quad; 64-127: k (transposed store); 128-191: v.
// Contains 1 barrier (all threads reach it).
__device__ __forceinline__ void qkv_row_v2(
    int i, int t, const float* __restrict__ snx,
    const float* __restrict__ Wq, const float* __restrict__ bq,
    const float* __restrict__ Wkv, const float* __restrict__ bkv,
    const float* __restrict__ We, const float* __restrict__ be,
    const float* __restrict__ cosRow, const float* __restrict__ sinRow,
    float* __restrict__ qb_, float* __restrict__ kbT, float* __restrict__ vb_,
    float* __restrict__ qWeB, float* __restrict__ qbeB,
    float4* __restrict__ qp4)     // LDS, 192 float4
{
  int ks   = (t < 192) ? 0 : 1;
  int quad = (t < 192) ? t : t - 192;
  float4 acc = {0.f, 0.f, 0.f, 0.f};
  if (t < 384){
    const float4* Wp; int stride4;
    if (quad < 64){ Wp = (const float4*)Wq + quad;         stride4 = 64;  }
    else          { Wp = (const float4*)Wkv + (quad - 64); stride4 = 128; }
    int k0 = ks * 64;
#pragma unroll 8
    for (int kk = 0; kk < 64; ++kk){
      int k = k0 + kk;
      float4 w = Wp[(size_t)k * stride4];
      float x = snx[k];
      acc.x = fmaf(x, w.x, acc.x); acc.y = fmaf(x, w.y, acc.y);
      acc.z = fmaf(x, w.z, acc.z); acc.w = fmaf(x, w.w, acc.w);
    }
    if (ks == 1) qp4[quad] = acc;
  }
  __syncthreads();
  if (t < 192){
    float4 p = qp4[quad];
    acc.x += p.x; acc.y += p.y; acc.z += p.z; acc.w += p.w;
    if (quad < 64){
      int c0 = 4 * quad;
      float4 b = ((const float4*)bq)[quad];
      float a0 = acc.x + b.x, a1 = acc.y + b.y, a2 = acc.z + b.z, a3 = acc.w + b.w;
      int d0 = c0 & 63;
      float c_0 = cosRow[d0],     s_0 = sinRow[d0];
      float c_1 = cosRow[d0 + 2], s_1 = sinRow[d0 + 2];
      float r0 = a0 * c_0 - a1 * s_0;
      float r1 = a1 * c_0 + a0 * s_0;
      float r2 = a2 * c_1 - a3 * s_1;
      float r3 = a3 * c_1 + a2 * s_1;
      float4 qv; qv.x = r0; qv.y = r1; qv.z = r2; qv.w = r3;
      *(float4*)(qb_ + (size_t)i * 256 + c0) = qv;
      int h = quad >> 4;
#pragma unroll
      for (int cc = 0; cc < 8; ++cc){
        const float* wc = We + cc * 256 + c0;
        float pr = r0 * wc[0] + r1 * wc[1] + r2 * wc[2] + r3 * wc[3];
#pragma unroll
        for (int m = 8; m >= 1; m >>= 1) pr += __shfl_xor(pr, m, 16);
        if ((t & 15) == 0) qWeB[(h * NTOK + i) * 8 + cc] = pr;
      }
      const float* bc = be + c0;
      float pb = r0 * bc[0] + r1 * bc[1] + r2 * bc[2] + r3 * bc[3];
#pragma unroll
      for (int m = 8; m >= 1; m >>= 1) pb += __shfl_xor(pb, m, 16);
      if ((t & 15) == 0) qbeB[h * NTOK + i] = pb;
    } else if (quad < 128){
      int c0 = 4 * (quad - 64);
      float4 b = ((const float4*)bkv)[quad - 64];
      float a0 = acc.x + b.x, a1 = acc.y + b.y, a2 = acc.z + b.z, a3 = acc.w + b.w;
      int d0 = c0 & 63, h = c0 >> 6;
      float c_0 = cosRow[d0],     s_0 = sinRow[d0];
      float c_1 = cosRow[d0 + 2], s_1 = sinRow[d0 + 2];
      float r0 = a0 * c_0 - a1 * s_0;
      float r1 = a1 * c_0 + a0 * s_0;
      float r2 = a2 * c_1 - a3 * s_1;
      float r3 = a3 * c_1 + a2 * s_1;
      float* kp = kbT + (size_t)(h * 64 + d0) * NTOK + i;
      kp[0]        = r0;
      kp[NTOK]     = r1;
      kp[2 * NTOK] = r2;
      kp[3 * NTOK] = r3;
    } else {
      int vq = quad - 128;
      int c0 = 4 * vq;
      float4 b = ((const float4*)bkv)[64 + vq];
      float4 vv;
      vv.x = acc.x + b.x; vv.y = acc.y + b.y;
      vv.z = acc.z + b.z; vv.w = acc.w + b.w;
      *(float4*)(vb_ + (size_t)i * 256 + c0) = vv;
    }
  }
}

// Layer-0: rotary + LN1 (single wave) + QKV. 512 thr/row.
__global__ __launch_bounds__(512) void k_lnqkv(
    const float* __restrict__ x,
    const float* __restrict__ ls, const float* __restrict__ lb,
    const float* __restrict__ Wq, const float* __restrict__ bq,
    const float* __restrict__ Wkv, const float* __restrict__ bkv,
    const float* __restrict__ We, const float* __restrict__ be,
    float* __restrict__ cosS, float* __restrict__ sinS,
    float* __restrict__ qb_, float* __restrict__ kbT, float* __restrict__ vb_,
    float* __restrict__ qWeB, float* __restrict__ qbeB)
{
  __shared__ float snx[128];
  __shared__ float crow[64], srow[64];
  __shared__ float4 qp4[192];
  int i = swz_row(blockIdx.x);
  int t = threadIdx.x;

  if (t >= 448){
    int d = t - 448;
    float c, s;
    rotary_val(i, d, &c, &s);
    crow[d] = c; srow[d] = s;
    cosS[i * 64 + d] = c; sinS[i * 64 + d] = s;
  }
  if (t < 64){
    float x0 = x[(size_t)i * 128 + t], x1 = x[(size_t)i * 128 + 64 + t];
    float mu = wave_sum64(x0 + x1) * (1.0f / 128.0f);
    float d0 = x0 - mu, d1 = x1 - mu;
    float var = wave_sum64(d0 * d0 + d1 * d1) * (1.0f / 128.0f);
    float rstd = 1.0f / sqrtf(var + 1e-3f);
    snx[t]      = d0 * rstd * ls[t]      + lb[t];
    snx[t + 64] = d1 * rstd * ls[t + 64] + lb[t + 64];
  }
  __syncthreads();
  qkv_row_v2(i, t, snx, Wq, bq, Wkv, bkv, We, be, crow, srow,
             qb_, kbT, vb_, qWeB, qbeB, qp4);
}

// Fused per-layer kernel: attention (4 heads) + proj + gates + LN2 + FFN
// (+ next-layer LN1 + QKV). One row per block, 512 threads.
__global__ __launch_bounds__(512) void k_layer(
    const float* __restrict__ qb_, const float* __restrict__ kbT, const float* __restrict__ vb_,
    const float* __restrict__ qWeB, const float* __restrict__ qbeB,
    const float* __restrict__ edges,
    const float* __restrict__ We, const float* __restrict__ be,    // layer L (attn epilogue)
    const float* __restrict__ Wo, const float* __restrict__ bo,
    const float* __restrict__ Wg_a,
    const float* __restrict__ ln2s, const float* __restrict__ ln2b,
    const float* __restrict__ W1, const float* __restrict__ b1,
    const float* __restrict__ W2, const float* __restrict__ b2,
    const float* __restrict__ Wg_f,
    const float* __restrict__ xin, float* __restrict__ xout,
    int has_next,
    const float* __restrict__ ls_n, const float* __restrict__ lb_n,
    const float* __restrict__ Wq_n, const float* __restrict__ bq_n,
    const float* __restrict__ Wkv_n, const float* __restrict__ bkv_n,
    const float* __restrict__ We_n, const float* __restrict__ be_n,
    const float* __restrict__ cosS, const float* __restrict__ sinS,
    float* __restrict__ qb_o, float* __restrict__ kbT_o, float* __restrict__ vb_o,
    float* __restrict__ qWeB_o, float* __restrict__ qbeB_o)
{
  __shared__ float qsL[256];
  __shared__ float qw[4][8];
  __shared__ float qbe[4];
  __shared__ float attnL[4][384];
  __shared__ float redA[8], redB[8];
  __shared__ float red8[8][8];
  __shared__ float part[512];
  __shared__ float ar[256];
  __shared__ float xold[128];
  __shared__ float xrow[128];
  __shared__ float snx[128];
  __shared__ float hs[512];
  __shared__ float4 prL[512];
  float* prF = (float*)prL;

  int i = swz_row(blockIdx.x);
  int t = threadIdx.x;

  // ---- stage q/qw/qbe/xold
  if (t < 256) qsL[t] = qb_[(size_t)i * 256 + t];
  else if (t < 288){ int idx = t - 256; qw[idx >> 3][idx & 7] = qWeB[((idx >> 3) * NTOK + i) * 8 + (idx & 7)]; }
  else if (t < 292) qbe[t - 288] = qbeB[(t - 288) * NTOK + i];
  else if (t >= 384) xold[t - 384] = xin[(size_t)i * 128 + (t - 384)];
  __syncthreads();

  // ---- sim: h = t>>7 (2 waves per head), jj = t&127, 3 j's per thread
  int h = t >> 7, jj = t & 127;
  int wv = t >> 6;
  float sims[3];
  float4 e0s[3], e1s[3];
  {
    float qbv = qbe[h];
    const float* qsp = qsL + h * 64;
#pragma unroll
    for (int rep = 0; rep < 3; ++rep){
      int j = jj + rep * 128;
      const float* kTp = kbT + (size_t)(h * 64) * NTOK + j;
      float a0 = 0.f, a1 = 0.f, a2 = 0.f, a3 = 0.f;
#pragma unroll 8
      for (int d = 0; d < 64; d += 4){
        a0 = fmaf(qsp[d],     kTp[(size_t)d * NTOK],       a0);
        a1 = fmaf(qsp[d + 1], kTp[(size_t)(d + 1) * NTOK], a1);
        a2 = fmaf(qsp[d + 2], kTp[(size_t)(d + 2) * NTOK], a2);
        a3 = fmaf(qsp[d + 3], kTp[(size_t)(d + 3) * NTOK], a3);
      }
      const float* ep = edges + ((size_t)i * NTOK + j) * 8;
      float4 e0 = *(const float4*)ep;
      float4 e1 = *(const float4*)(ep + 4);
      e0s[rep] = e0; e1s[rep] = e1;
      float ed = e0.x * qw[h][0] + e0.y * qw[h][1] + e0.z * qw[h][2] + e0.w * qw[h][3]
               + e1.x * qw[h][4] + e1.y * qw[h][5] + e1.z * qw[h][6] + e1.w * qw[h][7];
      sims[rep] = 0.125f * (a0 + a1 + a2 + a3 + ed + qbv);
    }
  }
  // ---- softmax per head (2 waves per head)
  float mx = wave_max64(fmaxf(sims[0], fmaxf(sims[1], sims[2])));
  if ((t & 63) == 0) redA[wv] = mx;
  __syncthreads();
  float gm = fmaxf(redA[2 * h], redA[2 * h + 1]);
  float ex0 = expf(sims[0] - gm), ex1 = expf(sims[1] - gm), ex2 = expf(sims[2] - gm);
  float sm = wave_sum64(ex0 + ex1 + ex2);
  if ((t & 63) == 0) redB[wv] = sm;
  __syncthreads();
  float inv = 1.0f / (redB[2 * h] + redB[2 * h + 1]);
  float w0 = ex0 * inv, w1 = ex1 * inv, w2 = ex2 * inv;
  attnL[h][jj] = w0; attnL[h][jj + 128] = w1; attnL[h][jj + 256] = w2;
  {
    float a8[8];
    a8[0] = w0 * e0s[0].x + w1 * e0s[1].x + w2 * e0s[2].x;
    a8[1] = w0 * e0s[0].y + w1 * e0s[1].y + w2 * e0s[2].y;
    a8[2] = w0 * e0s[0].z + w1 * e0s[1].z + w2 * e0s[2].z;
    a8[3] = w0 * e0s[0].w + w1 * e0s[1].w + w2 * e0s[2].w;
    a8[4] = w0 * e1s[0].x + w1 * e1s[1].x + w2 * e1s[2].x;
    a8[5] = w0 * e1s[0].y + w1 * e1s[1].y + w2 * e1s[2].y;
    a8[6] = w0 * e1s[0].z + w1 * e1s[1].z + w2 * e1s[2].z;
    a8[7] = w0 * e1s[0].w + w1 * e1s[1].w + w2 * e1s[2].w;
#pragma unroll
    for (int cc = 0; cc < 8; ++cc){
      float r = wave_sum64(a8[cc]);
      if ((t & 63) == 0) red8[wv][cc] = r;
    }
  }
  __syncthreads();   // attnL + red8 ready

  // ---- PV: t -> (h, d, half), 192 j each
  {
    int hh = t >> 7, dd = t & 63, half = (t >> 6) & 1;
    const float* vp = vb_ + hh * 64 + dd;
    const float* aw_ = attnL[hh];
    int j0 = half * 192;
    float va = 0.f, vb2 = 0.f;
#pragma unroll 8
    for (int jj2 = 0; jj2 < 192; jj2 += 2){
      va  = fmaf(aw_[j0 + jj2],     vp[(size_t)(j0 + jj2) * 256],     va);
      vb2 = fmaf(aw_[j0 + jj2 + 1], vp[(size_t)(j0 + jj2 + 1) * 256], vb2);
    }
    part[t] = va + vb2;
  }
  __syncthreads();
  if (t < 256){
    int h2 = t >> 6, d = t & 63;
    float o = part[h2 * 128 + d] + part[h2 * 128 + 64 + d];
    float ew = 0.f;
#pragma unroll
    for (int cc = 0; cc < 8; ++cc)
      ew = fmaf(red8[2 * h2][cc] + red8[2 * h2 + 1][cc], We[cc * 256 + h2 * 64 + d], ew);
    ar[t] = o + ew + be[h2 * 64 + d];
  }
  __syncthreads();

  // ---- proj: 128 outs, K=256. 32 colq x 16 ksub.
  {
    int colq = t & 31, ksub = t >> 5;
    const float4* Wo4 = (const float4*)Wo;
    float4 acc = {0.f, 0.f, 0.f, 0.f};
#pragma unroll
    for (int kk = 0; kk < 16; ++kk){
      int k = ksub * 16 + kk;
      float4 w = Wo4[(size_t)k * 32 + colq];
      float a = ar[k];
      acc.x = fmaf(a, w.x, acc.x); acc.y = fmaf(a, w.y, acc.y);
      acc.z = fmaf(a, w.z, acc.z); acc.w = fmaf(a, w.w, acc.w);
    }
    prL[ksub * 32 + colq] = acc;
  }
  __syncthreads();

  // ---- single-wave: proj-reduce + gate_a + LN2 (no internal barriers)
  if (t < 64){
    float o0 = bo[t], o1 = bo[t + 64];
#pragma unroll
    for (int s = 0; s < 16; ++s){ o0 += prF[s * 128 + t]; o1 += prF[s * 128 + 64 + t]; }
    float xo0 = xold[t], xo1 = xold[t + 64];
    float gp = o0 * Wg_a[t]      + xo0 * Wg_a[128 + t] + (o0 - xo0) * Wg_a[256 + t]
             + o1 * Wg_a[64 + t] + xo1 * Wg_a[192 + t] + (o1 - xo1) * Wg_a[320 + t];
    float z = wave_sum64(gp);
    float gg = 1.0f / (1.0f + expf(-z));
    float xr0 = o0 * gg + xo0 * (1.0f - gg);
    float xr1 = o1 * gg + xo1 * (1.0f - gg);
    xrow[t] = xr0; xrow[t + 64] = xr1;
    float mu = wave_sum64(xr0 + xr1) * (1.0f / 128.0f);
    float d0 = xr0 - mu, d1 = xr1 - mu;
    float var = wave_sum64(d0 * d0 + d1 * d1) * (1.0f / 128.0f);
    float rstd = 1.0f / sqrtf(var + 1e-3f);
    snx[t]      = d0 * rstd * ln2s[t]      + ln2b[t];
    snx[t + 64] = d1 * rstd * ln2s[t + 64] + ln2b[t + 64];
  }
  __syncthreads();

  // ---- FFN1: 512 outs, K=128. 128 colq x 4 ksub.
  {
    int colq = t & 127, ksub = t >> 7;
    const float4* W14 = (const float4*)W1;
    float4 acc = {0.f, 0.f, 0.f, 0.f};
#pragma unroll 8
    for (int kk = 0; kk < 32; ++kk){
      int k = ksub * 32 + kk;
      float4 w = W14[(size_t)k * 128 + colq];
      float a = snx[k];
      acc.x = fmaf(a, w.x, acc.x); acc.y = fmaf(a, w.y, acc.y);
      acc.z = fmaf(a, w.z, acc.z); acc.w = fmaf(a, w.w, acc.w);
    }
    prL[ksub * 128 + colq] = acc;
  }
  __syncthreads();

  // ---- GELU reduce -> hs
  {
    float hv = b1[t];
#pragma unroll
    for (int s3 = 0; s3 < 4; ++s3) hv += prF[s3 * 512 + t];
    const float RS2 = 0.70710678118654752440f;
    hs[t] = 0.5f * hv * (1.0f + erff(hv * RS2));
  }
  __syncthreads();

  // ---- FFN2: 128 outs, K=512. 32 colq x 16 ksub.
  {
    int colq = t & 31, ksub = t >> 5;
    const float4* W24 = (const float4*)W2;
    float4 acc = {0.f, 0.f, 0.f, 0.f};
#pragma unroll 8
    for (int kk = 0; kk < 32; ++kk){
      int k = ksub * 32 + kk;
      float4 w = W24[(size_t)k * 32 + colq];
      float a = hs[k];
      acc.x = fmaf(a, w.x, acc.x); acc.y = fmaf(a, w.y, acc.y);
      acc.z = fmaf(a, w.z, acc.z); acc.w = fmaf(a, w.w, acc.w);
    }
    prL[ksub * 32 + colq] = acc;
  }
  __syncthreads();

  // ---- single-wave: FFN2-reduce + gate_f + xnew + next-layer LN1
  if (t < 64){
    float f0 = b2[t], f1 = b2[t + 64];
#pragma unroll
    for (int s3 = 0; s3 < 16; ++s3){ f0 += prF[s3 * 128 + t]; f1 += prF[s3 * 128 + 64 + t]; }
    float xr0 = xrow[t], xr1 = xrow[t + 64];
    float gp = f0 * Wg_f[t]      + xr0 * Wg_f[128 + t] + (f0 - xr0) * Wg_f[256 + t]
             + f1 * Wg_f[64 + t] + xr1 * Wg_f[192 + t] + (f1 - xr1) * Wg_f[320 + t];
    float z = wave_sum64(gp);
    float gg = 1.0f / (1.0f + expf(-z));
    float xn0 = f0 * gg + xr0 * (1.0f - gg);
    float xn1 = f1 * gg + xr1 * (1.0f - gg);
    xout[(size_t)i * 128 + t]      = xn0;
    xout[(size_t)i * 128 + 64 + t] = xn1;
    if (has_next){
      float mu = wave_sum64(xn0 + xn1) * (1.0f / 128.0f);
      float d0 = xn0 - mu, d1 = xn1 - mu;
      float var = wave_sum64(d0 * d0 + d1 * d1) * (1.0f / 128.0f);
      float rstd = 1.0f / sqrtf(var + 1e-3f);
      snx[t]      = d0 * rstd * ls_n[t]      + lb_n[t];
      snx[t + 64] = d1 * rstd * ls_n[t + 64] + lb_n[t + 64];
    }
  }
  __syncthreads();

  if (has_next){
    qkv_row_v2(i, t, snx, Wq_n, bq_n, Wkv_n, bkv_n, We_n, be_n,
               cosS + (size_t)i * 64, sinS + (size_t)i * 64,
               qb_o, kbT_o, vb_o, qWeB_o, qbeB_o, prL);
  }
}

// Final head. Single block, 384 threads.
__global__ __launch_bounds__(384) void k_final(
    const float* __restrict__ x,
    const float* __restrict__ Wd1, const float* __restrict__ bd1,
    const float* __restrict__ Wd2, const float* __restrict__ bd2,
    float* __restrict__ out)
{
  __shared__ float red[6];
  int i = threadIdx.x;
  float y[9];
#pragma unroll
  for (int c = 0; c < 9; ++c) y[c] = bd1[c];
  const float4* x4 = (const float4*)(x + (size_t)i * 128);
#pragma unroll 8
  for (int r4 = 0; r4 < 32; ++r4){
    float4 xv = x4[r4];
    const float* wp = Wd1 + (r4 * 4) * 9;
#pragma unroll
    for (int c = 0; c < 9; ++c) y[c] = fmaf(xv.x, wp[c], y[c]);
#pragma unroll
    for (int c = 0; c < 9; ++c) y[c] = fmaf(xv.y, wp[9 + c], y[c]);
#pragma unroll
    for (int c = 0; c < 9; ++c) y[c] = fmaf(xv.z, wp[18 + c], y[c]);
#pragma unroll
    for (int c = 0; c < 9; ++c) y[c] = fmaf(xv.w, wp[27 + c], y[c]);
  }
#pragma unroll
  for (int c = 0; c < 9; ++c) y[c] = fmaxf(y[c], 0.0f);
  float z[3];
#pragma unroll
  for (int c = 0; c < 3; ++c){
    float a = bd2[c];
#pragma unroll
    for (int r = 0; r < 9; ++r) a = fmaf(y[r], Wd2[r * 3 + c], a);
    z[c] = a;
  }
#pragma unroll
  for (int c = 0; c < 3; ++c){
    float s = wave_sum64(z[c]);
    if ((i & 63) == 0) red[i >> 6] = s;
    __syncthreads();
    float tot = 0.f;
#pragma unroll
    for (int w = 0; w < 6; ++w) tot += red[w];
    float mean = tot * (1.0f / 384.0f);
    out[i * 3 + c] = z[c] - mean;
    __syncthreads();
  }
}

extern "C" void kernel_launch(void* const* d_in, const int* in_sizes, int n_in,
                              void* d_out, int out_size, void* d_ws, size_t ws_size,
                              hipStream_t stream)
{
  const float* nodes   = (const float*)d_in[0];
  const float* edges   = (const float*)d_in[1];
  const float* ln1_s   = (const float*)d_in[2];
  const float* ln1_b   = (const float*)d_in[3];
  const float* Wq      = (const float*)d_in[4];
  const float* bq      = (const float*)d_in[5];
  const float* Wkv     = (const float*)d_in[6];
  const float* bkv     = (const float*)d_in[7];
  const float* We      = (const float*)d_in[8];
  const float* be      = (const float*)d_in[9];
  const float* Wo      = (const float*)d_in[10];
  const float* bo      = (const float*)d_in[11];
  const float* Wg_attn = (const float*)d_in[12];
  const float* ln2_s   = (const float*)d_in[13];
  const float* ln2_b   = (const float*)d_in[14];
  const float* W1      = (const float*)d_in[15];
  const float* b1      = (const float*)d_in[16];
  const float* W2      = (const float*)d_in[17];
  const float* b2      = (const float*)d_in[18];
  const float* Wg_ff   = (const float*)d_in[19];
  const float* Wd1     = (const float*)d_in[20];
  const float* bd1     = (const float*)d_in[21];
  const float* Wd2     = (const float*)d_in[22];
  const float* bd2     = (const float*)d_in[23];
  // d_in[24] = mask: all-true; no-op in the math.

  float* ws   = (float*)d_ws;
  float* cosS = ws;                  // 384*64
  float* sinS = cosS + 24576;
  // double-buffered q/k/v sets (layer parity)
  float* qb0   = sinS + 24576;       // 384*256
  float* kbT0  = qb0 + 98304;        // [4][64][384]
  float* vb0   = kbT0 + 98304;
  float* qWe0  = vb0 + 98304;        // 4*384*8
  float* qbe0  = qWe0 + 12288;       // 4*384
  float* qb1   = qbe0 + 1536;
  float* kbT1  = qb1 + 98304;
  float* vb1   = kbT1 + 98304;
  float* qWe1  = vb1 + 98304;
  float* qbe1  = qWe1 + 12288;
  float* xbuf  = qbe1 + 1536;        // 384*128

  k_lnqkv<<<dim3(NTOK), dim3(512), 0, stream>>>(
      nodes, ln1_s, ln1_b, Wq, bq, Wkv, bkv, We, be,
      cosS, sinS, qb0, kbT0, vb0, qWe0, qbe0);

  for (int L = 0; L < DEPTH; ++L){
    int Ln = (L < DEPTH - 1) ? (L + 1) : L;
    const float* qbi  = (L & 1) ? qb1  : qb0;
    const float* kbi  = (L & 1) ? kbT1 : kbT0;
    const float* vbi  = (L & 1) ? vb1  : vb0;
    const float* qWei = (L & 1) ? qWe1 : qWe0;
    const float* qbei = (L & 1) ? qbe1 : qbe0;
    float* qbo  = (L & 1) ? qb0  : qb1;
    float* kbo  = (L & 1) ? kbT0 : kbT1;
    float* vbo  = (L & 1) ? vb0  : vb1;
    float* qWeo = (L & 1) ? qWe0 : qWe1;
    float* qbeo = (L & 1) ? qbe0 : qbe1;

    k_layer<<<dim3(NTOK), dim3(512), 0, stream>>>(
        qbi, kbi, vbi, qWei, qbei, edges,
        We + (size_t)L * EDGE * INNER, be + L * INNER,
        Wo + (size_t)L * INNER * DIM, bo + L * DIM,
        Wg_attn + L * 3 * DIM,
        ln2_s + L * DIM, ln2_b + L * DIM,
        W1 + (size_t)L * DIM * FFD, b1 + L * FFD,
        W2 + (size_t)L * FFD * DIM, b2 + L * DIM,
        Wg_ff + L * 3 * DIM,
        (L == 0) ? nodes : xbuf, xbuf,
        (L < DEPTH - 1) ? 1 : 0,
        ln1_s + Ln * DIM, ln1_b + Ln * DIM,
        Wq + (size_t)Ln * DIM * INNER, bq + Ln * INNER,
        Wkv + (size_t)Ln * DIM * 2 * INNER, bkv + Ln * 2 * INNER,
        We + (size_t)Ln * EDGE * INNER, be + Ln * INNER,
        cosS, sinS, qbo, kbo, vbo, qWeo, qbeo);
  }

  k_final<<<dim3(1), dim3(384), 0, stream>>>(xbuf, Wd1, bd1, Wd2, bd2, (float*)d_out);
}